// Round 12
// baseline (539.171 us; speedup 1.0000x reference)
//
#include <hip/hip_runtime.h>
#include <math.h>

#define NIMG 50000
#define NKN  8192
#define BB   32
#define DD   512
#define CC   32
#define RR   16
#define KK   8
#define MMAX 384   // max class-bucket size supported (mean 256, sd ~15.7)
#define NR   6     // KN rows per lane (6*64 = 384 = MMAX)

typedef float f16v __attribute__((ext_vector_type(16)));

// ---------------------------------------------------------------- class lists
__global__ __launch_bounds__(256) void build_lists(const int* __restrict__ labels,
                                                   int n, int* __restrict__ cnt,
                                                   int* __restrict__ list, int stride) {
    int i = blockIdx.x * 256 + threadIdx.x;
    if (i < n) {
        int c = labels[i];
        int pos = atomicAdd(&cnt[c], 1);
        list[c * stride + pos] = i;
    }
}

// ---------------------------------------------------------------- sims = Q @ I^T
__global__ __launch_bounds__(256) void sims_kernel(const float* __restrict__ Q,
                                                   const float* __restrict__ I,
                                                   float* __restrict__ S) {
    __shared__ float4 qs[BB * DD / 4];  // 64KB
    for (int i = threadIdx.x; i < BB * DD / 4; i += 256)
        qs[i] = ((const float4*)Q)[i];
    __syncthreads();
    int n = blockIdx.x * 256 + threadIdx.x;
    if (n >= NIMG) return;
    float acc[BB];
#pragma unroll
    for (int b = 0; b < BB; b++) acc[b] = 0.f;
    const float4* row = (const float4*)(I + (size_t)n * DD);
    for (int d4 = 0; d4 < DD / 4; d4++) {
        float4 v = row[d4];
#pragma unroll
        for (int b = 0; b < BB; b++) {
            float4 q = qs[b * (DD / 4) + d4];
            acc[b] += v.x * q.x + v.y * q.y + v.z * q.z + v.w * q.w;
        }
    }
#pragma unroll
    for (int b = 0; b < BB; b++) S[(size_t)b * NIMG + n] = acc[b];
}

// ---------------------------------------------------------------- top-16 images per (b,c)
__global__ __launch_bounds__(256) void topk_img(const float* __restrict__ S,
                                                const int* __restrict__ cnt,
                                                const int* __restrict__ list,
                                                int* __restrict__ t_idx,
                                                float* __restrict__ t_w) {
    int c = blockIdx.x, b = blockIdx.y, tid = threadIdx.x;
    __shared__ float sval[256 * RR];
    __shared__ int   sidx[256 * RR];
    __shared__ float redv[256];
    __shared__ int   redp[256];
    __shared__ float kv[RR];
    __shared__ int   ki[RR];

    float tv[RR]; int ti[RR];
#pragma unroll
    for (int k = 0; k < RR; k++) { tv[k] = -1e30f; ti[k] = 0; }

    int m = cnt[c];
    for (int j = tid; j < m; j += 256) {
        int n = list[c * NIMG + j];
        float v = S[(size_t)b * NIMG + n];
        if (v > tv[RR - 1]) {
            int p = RR - 1;
            while (p > 0 && tv[p - 1] < v) { tv[p] = tv[p - 1]; ti[p] = ti[p - 1]; p--; }
            tv[p] = v; ti[p] = n;
        }
    }
#pragma unroll
    for (int k = 0; k < RR; k++) { sval[tid * RR + k] = tv[k]; sidx[tid * RR + k] = ti[k]; }
    __syncthreads();

    for (int k = 0; k < RR; k++) {
        float bv = -1e30f; int bp = 0;
        for (int j = tid; j < 256 * RR; j += 256)
            if (sval[j] > bv) { bv = sval[j]; bp = j; }
        redv[tid] = bv; redp[tid] = bp;
        __syncthreads();
        for (int s = 128; s > 0; s >>= 1) {
            if (tid < s && redv[tid + s] > redv[tid]) { redv[tid] = redv[tid + s]; redp[tid] = redp[tid + s]; }
            __syncthreads();
        }
        if (tid == 0) { kv[k] = redv[0]; ki[k] = sidx[redp[0]]; sval[redp[0]] = -1e30f; }
        __syncthreads();
    }

    if (tid == 0) {
        float mx = kv[0], s = 0.f, e[RR];
#pragma unroll
        for (int k = 0; k < RR; k++) { e[k] = expf(kv[k] - mx); s += e[k]; }
        float inv = 1.f / s;
        size_t o = ((size_t)(b * CC) + c) * RR;
#pragma unroll
        for (int k = 0; k < RR; k++) { t_w[o + k] = e[k] * inv; t_idx[o + k] = ki[k]; }
    }
}

// ---------------------------------------------------------------- enhanced_images
__global__ __launch_bounds__(256) void img_kernel(const float* __restrict__ Q,
                                                  const float* __restrict__ I,
                                                  const int* __restrict__ t_idx,
                                                  const float* __restrict__ t_w,
                                                  float* __restrict__ out) {
    int c = blockIdx.x, b = blockIdx.y, tid = threadIdx.x;
    __shared__ float w[RR];
    __shared__ int   id[RR];
    if (tid < RR) {
        size_t o = ((size_t)(b * CC) + c) * RR;
        w[tid] = t_w[o + tid]; id[tid] = t_idx[o + tid];
    }
    __syncthreads();
    for (int d = tid; d < DD; d += 256) {
        float acc = 0.f;
#pragma unroll
        for (int r = 0; r < RR; r++) acc += w[r] * I[(size_t)id[r] * DD + d];
        out[((size_t)(b * CC) + c) * DD + d] = 0.5f * (Q[b * DD + d] + acc);
    }
}

// ---------------------------------------------------------------- gather-transpose
// KT4[c][d4][j] = float4(KN[klist[c][j]][4*d4 .. 4*d4+3]); j >= m clamps to
// class-row 0 (contents valid, masked at top-k). Written once, read 32x.
__global__ __launch_bounds__(256) void transpose_kn(const float* __restrict__ KN,
                                                    const int* __restrict__ kcnt,
                                                    const int* __restrict__ klist,
                                                    float4* __restrict__ KT4) {
    int c = blockIdx.x;
    int w = threadIdx.x >> 6, lane = threadIdx.x & 63;
    int j = blockIdx.y * 4 + w;              // 4 rows per block, 96 blocks.y
    int m = kcnt[c]; if (m > MMAX) m = MMAX;
    int row = klist[c * NKN + (j < m ? j : 0)];
    const float4* src = (const float4*)(KN + (size_t)row * DD);
    float4* dst = KT4 + (size_t)c * (DD / 4) * MMAX;
    float4 v0 = src[lane], v1 = src[lane + 64];
    dst[(size_t)lane * MMAX + j]        = v0;   // reads coalesced per row;
    dst[(size_t)(lane + 64) * MMAX + j] = v1;   // writes 16B-scattered (once)
}

// ---------------------------------------------------------------- knowledge v8
// v7 + coalesced K-stream: scoring reads the transposed KT4 tile, so each of
// the 6 loads per d4 covers 64 consecutive float4 (1KB contiguous); the whole
// class tile (768KB) is walked linearly and is L2/L3-resident across the 32
// b-blocks. Same summation order as v7 -> bitwise-identical scores.
__global__ __launch_bounds__(64, 1) void knowledge_kernel(const float* __restrict__ Q,
                                                          const float* __restrict__ I,
                                                          const float* __restrict__ KN,
                                                          const float4* __restrict__ KT4,
                                                          const int* __restrict__ kcnt,
                                                          const int* __restrict__ klist,
                                                          const int* __restrict__ t_idx,
                                                          const float* __restrict__ t_w,
                                                          float* __restrict__ outk) {
    int c = blockIdx.x, b = blockIdx.y, lane = threadIdx.x;

    __shared__ float4 simg[RR][DD / 4];   // 32 KB: 16 retrieved image rows
    __shared__ float  s_iw[RR];
    __shared__ int    s_ii[RR];
    __shared__ float  wgt[RR][KK];        // combined weights iw_r * softmax_k
    __shared__ int    kidx[RR][KK];       // selected KN global row indices

    if (lane < RR) {
        size_t o = ((size_t)(b * CC) + c) * RR;
        s_iw[lane] = t_w[o + lane]; s_ii[lane] = t_idx[o + lane];
    }
    __syncthreads();

    // stage 16 image rows: each row = 128 float4, 2 per lane
#pragma unroll
    for (int r = 0; r < RR; r++) {
        const float4* src = (const float4*)(I + (size_t)s_ii[r] * DD);
        simg[r][lane]      = src[lane];
        simg[r][lane + 64] = src[lane + 64];
    }

    int m = kcnt[c]; if (m > MMAX) m = MMAX;
    const float4* KTc = KT4 + (size_t)c * (DD / 4) * MMAX;

    f16v A0 = 0.f, A1 = 0.f, A2 = 0.f, A3 = 0.f, A4 = 0.f, A5 = 0.f;

    __syncthreads();

    // ---- scoring: 2-deep pipelined, coalesced, all state named SSA
#define LD_SET(K0, K1, K2, K3, K4, K5, D4) { \
        const float4* p = KTc + (size_t)(D4) * MMAX + lane; \
        K0 = p[0]; K1 = p[64]; K2 = p[128]; K3 = p[192]; K4 = p[256]; K5 = p[320]; }

#define SC_R(r, K0, K1, K2, K3, K4, K5, D4) { float4 u = simg[r][D4]; \
        A0[r] += K0.x*u.x + K0.y*u.y + K0.z*u.z + K0.w*u.w; \
        A1[r] += K1.x*u.x + K1.y*u.y + K1.z*u.z + K1.w*u.w; \
        A2[r] += K2.x*u.x + K2.y*u.y + K2.z*u.z + K2.w*u.w; \
        A3[r] += K3.x*u.x + K3.y*u.y + K3.z*u.z + K3.w*u.w; \
        A4[r] += K4.x*u.x + K4.y*u.y + K4.z*u.z + K4.w*u.w; \
        A5[r] += K5.x*u.x + K5.y*u.y + K5.z*u.z + K5.w*u.w; }

#define SC_ALL(K0, K1, K2, K3, K4, K5, D4) \
        SC_R(0,  K0,K1,K2,K3,K4,K5, D4) SC_R(1,  K0,K1,K2,K3,K4,K5, D4) \
        SC_R(2,  K0,K1,K2,K3,K4,K5, D4) SC_R(3,  K0,K1,K2,K3,K4,K5, D4) \
        SC_R(4,  K0,K1,K2,K3,K4,K5, D4) SC_R(5,  K0,K1,K2,K3,K4,K5, D4) \
        SC_R(6,  K0,K1,K2,K3,K4,K5, D4) SC_R(7,  K0,K1,K2,K3,K4,K5, D4) \
        SC_R(8,  K0,K1,K2,K3,K4,K5, D4) SC_R(9,  K0,K1,K2,K3,K4,K5, D4) \
        SC_R(10, K0,K1,K2,K3,K4,K5, D4) SC_R(11, K0,K1,K2,K3,K4,K5, D4) \
        SC_R(12, K0,K1,K2,K3,K4,K5, D4) SC_R(13, K0,K1,K2,K3,K4,K5, D4) \
        SC_R(14, K0,K1,K2,K3,K4,K5, D4) SC_R(15, K0,K1,K2,K3,K4,K5, D4)

    float4 ak0, ak1, ak2, ak3, ak4, ak5;
    float4 bk0, bk1, bk2, bk3, bk4, bk5;
    LD_SET(ak0, ak1, ak2, ak3, ak4, ak5, 0)

    for (int d4 = 0; d4 < DD / 4; d4 += 2) {
        LD_SET(bk0, bk1, bk2, bk3, bk4, bk5, d4 + 1)
        SC_ALL(ak0, ak1, ak2, ak3, ak4, ak5, d4)
        int nx = (d4 + 2 < DD / 4) ? (d4 + 2) : (DD / 4 - 1);
        LD_SET(ak0, ak1, ak2, ak3, ak4, ak5, nx)
        SC_ALL(bk0, bk1, bk2, bk3, bk4, bk5, d4 + 1)
    }
#undef SC_ALL
#undef SC_R
#undef LD_SET

    // ---- per-r top-8 (wave shuffle argmax, lexicographic) + softmax
#define CAND(t) { if (!(used & (1u << t)) && \
                      (lv##t > mv || (lv##t == mv && (t * 64 + lane) < mj))) \
                  { mv = lv##t; mj = t * 64 + lane; mt = t; } }

#define ROUND(k) { \
        float mv = -1e30f; int mj = 0x7fffffff; int mt = -1; \
        CAND(0) CAND(1) CAND(2) CAND(3) CAND(4) CAND(5) \
        int cj = mj; \
        for (int off = 32; off > 0; off >>= 1) { \
            float ov = __shfl_xor(mv, off); \
            int   oj = __shfl_xor(mj, off); \
            if (ov > mv || (ov == mv && oj < mj)) { mv = ov; mj = oj; } \
        } \
        if (cj == mj && mt >= 0) used |= (1u << mt); \
        if (lane == k) myj = mj; \
        kv##k = mv; }

#define TOPK_R(r) { \
        float lv0 = (0 * 64 + lane < m) ? A0[r] : -1e30f; \
        float lv1 = (1 * 64 + lane < m) ? A1[r] : -1e30f; \
        float lv2 = (2 * 64 + lane < m) ? A2[r] : -1e30f; \
        float lv3 = (3 * 64 + lane < m) ? A3[r] : -1e30f; \
        float lv4 = (4 * 64 + lane < m) ? A4[r] : -1e30f; \
        float lv5 = (5 * 64 + lane < m) ? A5[r] : -1e30f; \
        unsigned used = 0; int myj = 0; \
        float kv0, kv1, kv2, kv3, kv4, kv5, kv6, kv7; \
        ROUND(0) ROUND(1) ROUND(2) ROUND(3) \
        ROUND(4) ROUND(5) ROUND(6) ROUND(7) \
        if (lane < KK) kidx[r][lane] = klist[c * NKN + myj]; \
        if (lane == 0) { \
            float e0 = 1.f;                 /* expf(kv0-kv0) */ \
            float e1 = expf(kv1 - kv0), e2 = expf(kv2 - kv0), e3 = expf(kv3 - kv0); \
            float e4 = expf(kv4 - kv0), e5 = expf(kv5 - kv0), e6 = expf(kv6 - kv0); \
            float e7 = expf(kv7 - kv0); \
            float s = e0 + e1 + e2 + e3 + e4 + e5 + e6 + e7; \
            float wr = s_iw[r] / s; \
            wgt[r][0] = e0 * wr; wgt[r][1] = e1 * wr; wgt[r][2] = e2 * wr; \
            wgt[r][3] = e3 * wr; wgt[r][4] = e4 * wr; wgt[r][5] = e5 * wr; \
            wgt[r][6] = e6 * wr; wgt[r][7] = e7 * wr; \
        } }

    TOPK_R(0)  TOPK_R(1)  TOPK_R(2)  TOPK_R(3)
    TOPK_R(4)  TOPK_R(5)  TOPK_R(6)  TOPK_R(7)
    TOPK_R(8)  TOPK_R(9)  TOPK_R(10) TOPK_R(11)
    TOPK_R(12) TOPK_R(13) TOPK_R(14) TOPK_R(15)
#undef TOPK_R
#undef ROUND
#undef CAND

    __syncthreads();

    // ---- gather-accumulate: lane handles dims [lane*4..+3] and [256+lane*4..+3]
    float4 a0 = {0.f, 0.f, 0.f, 0.f}, a1 = {0.f, 0.f, 0.f, 0.f};
#pragma unroll 8
    for (int p = 0; p < RR * KK; p++) {
        int r = p >> 3, k = p & 7;
        float w = wgt[r][k];
        const float4* kp = (const float4*)(KN + (size_t)kidx[r][k] * DD);
        float4 v0 = kp[lane], v1 = kp[lane + 64];
        a0.x += w * v0.x; a0.y += w * v0.y; a0.z += w * v0.z; a0.w += w * v0.w;
        a1.x += w * v1.x; a1.y += w * v1.y; a1.z += w * v1.z; a1.w += w * v1.w;
    }
    const float4* q4 = (const float4*)(Q + (size_t)b * DD);
    float4 q0 = q4[lane], q1 = q4[lane + 64];
    float4 o0, o1;
    o0.x = 0.5f * (q0.x + a0.x); o0.y = 0.5f * (q0.y + a0.y);
    o0.z = 0.5f * (q0.z + a0.z); o0.w = 0.5f * (q0.w + a0.w);
    o1.x = 0.5f * (q1.x + a1.x); o1.y = 0.5f * (q1.y + a1.y);
    o1.z = 0.5f * (q1.z + a1.z); o1.w = 0.5f * (q1.w + a1.w);
    float4* out4 = (float4*)(outk + ((size_t)(b * CC) + c) * DD);
    out4[lane]      = o0;
    out4[lane + 64] = o1;
}

// ---------------------------------------------------------------- launch
extern "C" void kernel_launch(void* const* d_in, const int* in_sizes, int n_in,
                              void* d_out, int out_size, void* d_ws, size_t ws_size,
                              hipStream_t stream) {
    const float* Q  = (const float*)d_in[0];
    const float* I  = (const float*)d_in[1];
    const float* KN = (const float*)d_in[2];
    const int* ilab = (const int*)d_in[3];
    const int* klab = (const int*)d_in[4];

    char* ws = (char*)d_ws;
    float* S        = (float*)ws;  ws += (size_t)BB * NIMG * 4;
    int*   img_list = (int*)ws;    ws += (size_t)CC * NIMG * 4;
    int*   kn_list  = (int*)ws;    ws += (size_t)CC * NKN * 4;
    int*   t_idx    = (int*)ws;    ws += (size_t)BB * CC * RR * 4;
    float* t_w      = (float*)ws;  ws += (size_t)BB * CC * RR * 4;
    int*   img_cnt  = (int*)ws;    ws += CC * 4;
    int*   kn_cnt   = (int*)ws;    ws += CC * 4;
    ws = (char*)(((size_t)ws + 255) & ~(size_t)255);   // align 256B
    float4* KT4     = (float4*)ws; ws += (size_t)CC * (DD / 4) * MMAX * 16;  // 25.2 MB

    float* out_img = (float*)d_out;
    float* out_kn  = out_img + (size_t)BB * CC * DD;

    hipMemsetAsync(img_cnt, 0, 2 * CC * 4, stream);  // img_cnt + kn_cnt contiguous

    build_lists<<<(NIMG + 255) / 256, 256, 0, stream>>>(ilab, NIMG, img_cnt, img_list, NIMG);
    build_lists<<<(NKN  + 255) / 256, 256, 0, stream>>>(klab, NKN,  kn_cnt,  kn_list,  NKN);
    transpose_kn<<<dim3(CC, MMAX / 4), 256, 0, stream>>>(KN, kn_cnt, kn_list, KT4);
    sims_kernel<<<(NIMG + 255) / 256, 256, 0, stream>>>(Q, I, S);
    topk_img<<<dim3(CC, BB), 256, 0, stream>>>(S, img_cnt, img_list, t_idx, t_w);
    img_kernel<<<dim3(CC, BB), 256, 0, stream>>>(Q, I, t_idx, t_w, (float*)d_out);
    knowledge_kernel<<<dim3(CC, BB), 64, 0, stream>>>(Q, I, KN, KT4, kn_cnt, kn_list, t_idx, t_w, out_kn);
}

// Round 14
// 429.184 us; speedup vs baseline: 1.2563x; 1.2563x over previous
//
#include <hip/hip_runtime.h>
#include <math.h>

#define NIMG 50000
#define NKN  8192
#define BB   32
#define DD   512
#define CC   32
#define RR   16
#define KK   8
#define MMAX 384   // max class-bucket size supported (mean 256, sd ~15.7)

typedef float f4v __attribute__((ext_vector_type(4)));

// ---------------------------------------------------------------- class lists
__global__ __launch_bounds__(256) void build_lists(const int* __restrict__ labels,
                                                   int n, int* __restrict__ cnt,
                                                   int* __restrict__ list, int stride) {
    int i = blockIdx.x * 256 + threadIdx.x;
    if (i < n) {
        int c = labels[i];
        int pos = atomicAdd(&cnt[c], 1);
        list[c * stride + pos] = i;
    }
}

// ---------------------------------------------------------------- sims = Q @ I^T
__global__ __launch_bounds__(256) void sims_kernel(const float* __restrict__ Q,
                                                   const float* __restrict__ I,
                                                   float* __restrict__ S) {
    __shared__ float4 qs[BB * DD / 4];  // 64KB
    for (int i = threadIdx.x; i < BB * DD / 4; i += 256)
        qs[i] = ((const float4*)Q)[i];
    __syncthreads();
    int n = blockIdx.x * 256 + threadIdx.x;
    if (n >= NIMG) return;
    float acc[BB];
#pragma unroll
    for (int b = 0; b < BB; b++) acc[b] = 0.f;
    const float4* row = (const float4*)(I + (size_t)n * DD);
    for (int d4 = 0; d4 < DD / 4; d4++) {
        float4 v = row[d4];
#pragma unroll
        for (int b = 0; b < BB; b++) {
            float4 q = qs[b * (DD / 4) + d4];
            acc[b] += v.x * q.x + v.y * q.y + v.z * q.z + v.w * q.w;
        }
    }
#pragma unroll
    for (int b = 0; b < BB; b++) S[(size_t)b * NIMG + n] = acc[b];
}

// ---------------------------------------------------------------- top-16 images per (b,c)
__global__ __launch_bounds__(256) void topk_img(const float* __restrict__ S,
                                                const int* __restrict__ cnt,
                                                const int* __restrict__ list,
                                                int* __restrict__ t_idx,
                                                float* __restrict__ t_w) {
    int c = blockIdx.x, b = blockIdx.y, tid = threadIdx.x;
    __shared__ float sval[256 * RR];
    __shared__ int   sidx[256 * RR];
    __shared__ float redv[256];
    __shared__ int   redp[256];
    __shared__ float kv[RR];
    __shared__ int   ki[RR];

    float tv[RR]; int ti[RR];
#pragma unroll
    for (int k = 0; k < RR; k++) { tv[k] = -1e30f; ti[k] = 0; }

    int m = cnt[c];
    for (int j = tid; j < m; j += 256) {
        int n = list[c * NIMG + j];
        float v = S[(size_t)b * NIMG + n];
        if (v > tv[RR - 1]) {
            int p = RR - 1;
            while (p > 0 && tv[p - 1] < v) { tv[p] = tv[p - 1]; ti[p] = ti[p - 1]; p--; }
            tv[p] = v; ti[p] = n;
        }
    }
#pragma unroll
    for (int k = 0; k < RR; k++) { sval[tid * RR + k] = tv[k]; sidx[tid * RR + k] = ti[k]; }
    __syncthreads();

    for (int k = 0; k < RR; k++) {
        float bv = -1e30f; int bp = 0;
        for (int j = tid; j < 256 * RR; j += 256)
            if (sval[j] > bv) { bv = sval[j]; bp = j; }
        redv[tid] = bv; redp[tid] = bp;
        __syncthreads();
        for (int s = 128; s > 0; s >>= 1) {
            if (tid < s && redv[tid + s] > redv[tid]) { redv[tid] = redv[tid + s]; redp[tid] = redp[tid + s]; }
            __syncthreads();
        }
        if (tid == 0) { kv[k] = redv[0]; ki[k] = sidx[redp[0]]; sval[redp[0]] = -1e30f; }
        __syncthreads();
    }

    if (tid == 0) {
        float mx = kv[0], s = 0.f, e[RR];
#pragma unroll
        for (int k = 0; k < RR; k++) { e[k] = expf(kv[k] - mx); s += e[k]; }
        float inv = 1.f / s;
        size_t o = ((size_t)(b * CC) + c) * RR;
#pragma unroll
        for (int k = 0; k < RR; k++) { t_w[o + k] = e[k] * inv; t_idx[o + k] = ki[k]; }
    }
}

// ---------------------------------------------------------------- enhanced_images
__global__ __launch_bounds__(256) void img_kernel(const float* __restrict__ Q,
                                                  const float* __restrict__ I,
                                                  const int* __restrict__ t_idx,
                                                  const float* __restrict__ t_w,
                                                  float* __restrict__ out) {
    int c = blockIdx.x, b = blockIdx.y, tid = threadIdx.x;
    __shared__ float w[RR];
    __shared__ int   id[RR];
    if (tid < RR) {
        size_t o = ((size_t)(b * CC) + c) * RR;
        w[tid] = t_w[o + tid]; id[tid] = t_idx[o + tid];
    }
    __syncthreads();
    for (int d = tid; d < DD; d += 256) {
        float acc = 0.f;
#pragma unroll
        for (int r = 0; r < RR; r++) acc += w[r] * I[(size_t)id[r] * DD + d];
        out[((size_t)(b * CC) + c) * DD + d] = 0.5f * (Q[b * DD + d] + acc);
    }
}

// ---------------------------------------------------------------- gather-transpose
// KT4[c][d4][j] = float4(KN[klist[c][j]][4*d4 .. 4*d4+3]); j >= m clamps to
// class-row 0 (contents valid, masked at top-k). Written once, read 32x.
__global__ __launch_bounds__(256) void transpose_kn(const float* __restrict__ KN,
                                                    const int* __restrict__ kcnt,
                                                    const int* __restrict__ klist,
                                                    float4* __restrict__ KT4) {
    int c = blockIdx.x;
    int w = threadIdx.x >> 6, lane = threadIdx.x & 63;
    int j = blockIdx.y * 4 + w;              // 4 rows per block, 96 blocks.y
    int m = kcnt[c]; if (m > MMAX) m = MMAX;
    int row = klist[c * NKN + (j < m ? j : 0)];
    const float4* src = (const float4*)(KN + (size_t)row * DD);
    float4* dst = KT4 + (size_t)c * (DD / 4) * MMAX;
    float4 v0 = src[lane], v1 = src[lane + 64];
    dst[(size_t)lane * MMAX + j]        = v0;   // reads coalesced per row;
    dst[(size_t)(lane + 64) * MMAX + j] = v1;   // writes 16B-scattered (once)
}

// ---------------------------------------------------------------- knowledge v9
// 4 waves per block, same (b,c): wave w owns r = 4w..4w+3 and scans the full
// class m-range (6 KT4 rows/lane, f4v accumulators). The 32KB simg tile is
// shared by all 4 waves -> 4 blocks/CU x 4 waves = 4 waves/SIMD of TLP, which
// is what the single-wave v7/v8 lacked (latency-serialized, VALUBusy 33%).
// Scoring sum order (d4 ascending, xyzw) identical to v7/v8 -> same top-k.
__global__ __launch_bounds__(256, 4) void knowledge_kernel(const float* __restrict__ Q,
                                                           const float* __restrict__ I,
                                                           const float* __restrict__ KN,
                                                           const float4* __restrict__ KT4,
                                                           const int* __restrict__ kcnt,
                                                           const int* __restrict__ klist,
                                                           const int* __restrict__ t_idx,
                                                           const float* __restrict__ t_w,
                                                           float* __restrict__ outk) {
    int c = blockIdx.x, b = blockIdx.y;
    int tid = threadIdx.x, wave = tid >> 6, lane = tid & 63;
    int rbase = wave * 4;

    __shared__ float4 simg[RR][DD / 4];   // 32 KB, shared by all 4 waves
    __shared__ float  s_iw[RR];
    __shared__ int    s_ii[RR];
    __shared__ float  wgt[RR][KK];
    __shared__ int    kidx[RR][KK];

    if (tid < RR) {
        size_t o = ((size_t)(b * CC) + c) * RR;
        s_iw[tid] = t_w[o + tid]; s_ii[tid] = t_idx[o + tid];
    }
    __syncthreads();

    // cooperative stage: 2048 float4, 8 per thread
    for (int i = tid; i < RR * DD / 4; i += 256) {
        int r = i >> 7, d4 = i & 127;
        simg[r][d4] = ((const float4*)(I + (size_t)s_ii[r] * DD))[d4];
    }

    int m = kcnt[c]; if (m > MMAX) m = MMAX;
    const float4* KTc = KT4 + (size_t)c * (DD / 4) * MMAX;

    f4v A0 = 0.f, A1 = 0.f, A2 = 0.f, A3 = 0.f, A4 = 0.f, A5 = 0.f;

    __syncthreads();

    // ---- scoring: wave handles its 4 r's over all 384 class rows
#define SC_RR(rr) { float4 u = simg[rbase + rr][d4]; \
        A0[rr] += k0.x*u.x + k0.y*u.y + k0.z*u.z + k0.w*u.w; \
        A1[rr] += k1.x*u.x + k1.y*u.y + k1.z*u.z + k1.w*u.w; \
        A2[rr] += k2.x*u.x + k2.y*u.y + k2.z*u.z + k2.w*u.w; \
        A3[rr] += k3.x*u.x + k3.y*u.y + k3.z*u.z + k3.w*u.w; \
        A4[rr] += k4.x*u.x + k4.y*u.y + k4.z*u.z + k4.w*u.w; \
        A5[rr] += k5.x*u.x + k5.y*u.y + k5.z*u.z + k5.w*u.w; }

    for (int d4 = 0; d4 < DD / 4; d4++) {
        const float4* p = KTc + (size_t)d4 * MMAX + lane;
        float4 k0 = p[0],   k1 = p[64],  k2 = p[128],
               k3 = p[192], k4 = p[256], k5 = p[320];
        SC_RR(0) SC_RR(1) SC_RR(2) SC_RR(3)
    }
#undef SC_RR

    // ---- per-r top-8 (wave-local shuffle argmax, lexicographic) + softmax
#define CAND(t) { if (!(used & (1u << t)) && \
                      (lv##t > mv || (lv##t == mv && (t * 64 + lane) < mj))) \
                  { mv = lv##t; mj = t * 64 + lane; mt = t; } }

#define ROUND(k) { \
        float mv = -1e30f; int mj = 0x7fffffff; int mt = -1; \
        CAND(0) CAND(1) CAND(2) CAND(3) CAND(4) CAND(5) \
        int cj = mj; \
        for (int off = 32; off > 0; off >>= 1) { \
            float ov = __shfl_xor(mv, off); \
            int   oj = __shfl_xor(mj, off); \
            if (ov > mv || (ov == mv && oj < mj)) { mv = ov; mj = oj; } \
        } \
        if (cj == mj && mt >= 0) used |= (1u << mt); \
        if (lane == k) myj = mj; \
        kv##k = mv; }

#define TOPK_RR(rr) { \
        int r = rbase + rr; \
        float lv0 = (0 * 64 + lane < m) ? A0[rr] : -1e30f; \
        float lv1 = (1 * 64 + lane < m) ? A1[rr] : -1e30f; \
        float lv2 = (2 * 64 + lane < m) ? A2[rr] : -1e30f; \
        float lv3 = (3 * 64 + lane < m) ? A3[rr] : -1e30f; \
        float lv4 = (4 * 64 + lane < m) ? A4[rr] : -1e30f; \
        float lv5 = (5 * 64 + lane < m) ? A5[rr] : -1e30f; \
        unsigned used = 0; int myj = 0; \
        float kv0, kv1, kv2, kv3, kv4, kv5, kv6, kv7; \
        ROUND(0) ROUND(1) ROUND(2) ROUND(3) \
        ROUND(4) ROUND(5) ROUND(6) ROUND(7) \
        if (lane < KK) kidx[r][lane] = klist[c * NKN + myj]; \
        if (lane == 0) { \
            float e0 = 1.f; \
            float e1 = expf(kv1 - kv0), e2 = expf(kv2 - kv0), e3 = expf(kv3 - kv0); \
            float e4 = expf(kv4 - kv0), e5 = expf(kv5 - kv0), e6 = expf(kv6 - kv0); \
            float e7 = expf(kv7 - kv0); \
            float s = e0 + e1 + e2 + e3 + e4 + e5 + e6 + e7; \
            float wr = s_iw[r] / s; \
            wgt[r][0] = e0 * wr; wgt[r][1] = e1 * wr; wgt[r][2] = e2 * wr; \
            wgt[r][3] = e3 * wr; wgt[r][4] = e4 * wr; wgt[r][5] = e5 * wr; \
            wgt[r][6] = e6 * wr; wgt[r][7] = e7 * wr; \
        } }

    TOPK_RR(0) TOPK_RR(1) TOPK_RR(2) TOPK_RR(3)
#undef TOPK_RR
#undef ROUND
#undef CAND

    __syncthreads();

    // ---- gather-accumulate: 256 threads, dims tid and tid+256
    float acc0 = 0.f, acc1 = 0.f;
#pragma unroll 8
    for (int p = 0; p < RR * KK; p++) {
        int r = p >> 3, k = p & 7;
        float w = wgt[r][k];
        const float* kp = KN + (size_t)kidx[r][k] * DD;
        acc0 += w * kp[tid];
        acc1 += w * kp[tid + 256];
    }
    size_t o = ((size_t)(b * CC) + c) * DD;
    outk[o + tid]       = 0.5f * (Q[b * DD + tid] + acc0);
    outk[o + tid + 256] = 0.5f * (Q[b * DD + tid + 256] + acc1);
}

// ---------------------------------------------------------------- launch
extern "C" void kernel_launch(void* const* d_in, const int* in_sizes, int n_in,
                              void* d_out, int out_size, void* d_ws, size_t ws_size,
                              hipStream_t stream) {
    const float* Q  = (const float*)d_in[0];
    const float* I  = (const float*)d_in[1];
    const float* KN = (const float*)d_in[2];
    const int* ilab = (const int*)d_in[3];
    const int* klab = (const int*)d_in[4];

    char* ws = (char*)d_ws;
    float* S        = (float*)ws;  ws += (size_t)BB * NIMG * 4;
    int*   img_list = (int*)ws;    ws += (size_t)CC * NIMG * 4;
    int*   kn_list  = (int*)ws;    ws += (size_t)CC * NKN * 4;
    int*   t_idx    = (int*)ws;    ws += (size_t)BB * CC * RR * 4;
    float* t_w      = (float*)ws;  ws += (size_t)BB * CC * RR * 4;
    int*   img_cnt  = (int*)ws;    ws += CC * 4;
    int*   kn_cnt   = (int*)ws;    ws += CC * 4;
    ws = (char*)(((size_t)ws + 255) & ~(size_t)255);   // align 256B
    float4* KT4     = (float4*)ws; ws += (size_t)CC * (DD / 4) * MMAX * 16;  // 25.2 MB

    float* out_img = (float*)d_out;
    float* out_kn  = out_img + (size_t)BB * CC * DD;

    hipMemsetAsync(img_cnt, 0, 2 * CC * 4, stream);  // img_cnt + kn_cnt contiguous

    build_lists<<<(NIMG + 255) / 256, 256, 0, stream>>>(ilab, NIMG, img_cnt, img_list, NIMG);
    build_lists<<<(NKN  + 255) / 256, 256, 0, stream>>>(klab, NKN,  kn_cnt,  kn_list,  NKN);
    transpose_kn<<<dim3(CC, MMAX / 4), 256, 0, stream>>>(KN, kn_cnt, kn_list, KT4);
    sims_kernel<<<(NIMG + 255) / 256, 256, 0, stream>>>(Q, I, S);
    topk_img<<<dim3(CC, BB), 256, 0, stream>>>(S, img_cnt, img_list, t_idx, t_w);
    img_kernel<<<dim3(CC, BB), 256, 0, stream>>>(Q, I, t_idx, t_w, (float*)d_out);
    knowledge_kernel<<<dim3(CC, BB), 256, 0, stream>>>(Q, I, KN, KT4, kn_cnt, kn_list, t_idx, t_w, out_kn);
}

// Round 15
// 423.472 us; speedup vs baseline: 1.2732x; 1.0135x over previous
//
#include <hip/hip_runtime.h>
#include <math.h>

#define NIMG 50000
#define NKN  8192
#define BB   32
#define DD   512
#define CC   32
#define RR   16
#define KK   8
#define MMAX 384   // max class-bucket size supported (mean 256, sd ~15.7)

typedef float f2v __attribute__((ext_vector_type(2)));

// ---------------------------------------------------------------- class lists
__global__ __launch_bounds__(256) void build_lists(const int* __restrict__ labels,
                                                   int n, int* __restrict__ cnt,
                                                   int* __restrict__ list, int stride) {
    int i = blockIdx.x * 256 + threadIdx.x;
    if (i < n) {
        int c = labels[i];
        int pos = atomicAdd(&cnt[c], 1);
        list[c * stride + pos] = i;
    }
}

// ---------------------------------------------------------------- sims = Q @ I^T
__global__ __launch_bounds__(256) void sims_kernel(const float* __restrict__ Q,
                                                   const float* __restrict__ I,
                                                   float* __restrict__ S) {
    __shared__ float4 qs[BB * DD / 4];  // 64KB
    for (int i = threadIdx.x; i < BB * DD / 4; i += 256)
        qs[i] = ((const float4*)Q)[i];
    __syncthreads();
    int n = blockIdx.x * 256 + threadIdx.x;
    if (n >= NIMG) return;
    float acc[BB];
#pragma unroll
    for (int b = 0; b < BB; b++) acc[b] = 0.f;
    const float4* row = (const float4*)(I + (size_t)n * DD);
    for (int d4 = 0; d4 < DD / 4; d4++) {
        float4 v = row[d4];
#pragma unroll
        for (int b = 0; b < BB; b++) {
            float4 q = qs[b * (DD / 4) + d4];
            acc[b] += v.x * q.x + v.y * q.y + v.z * q.z + v.w * q.w;
        }
    }
#pragma unroll
    for (int b = 0; b < BB; b++) S[(size_t)b * NIMG + n] = acc[b];
}

// ---------------------------------------------------------------- top-16 images per (b,c)
__global__ __launch_bounds__(256) void topk_img(const float* __restrict__ S,
                                                const int* __restrict__ cnt,
                                                const int* __restrict__ list,
                                                int* __restrict__ t_idx,
                                                float* __restrict__ t_w) {
    int c = blockIdx.x, b = blockIdx.y, tid = threadIdx.x;
    __shared__ float sval[256 * RR];
    __shared__ int   sidx[256 * RR];
    __shared__ float redv[256];
    __shared__ int   redp[256];
    __shared__ float kv[RR];
    __shared__ int   ki[RR];

    float tv[RR]; int ti[RR];
#pragma unroll
    for (int k = 0; k < RR; k++) { tv[k] = -1e30f; ti[k] = 0; }

    int m = cnt[c];
    for (int j = tid; j < m; j += 256) {
        int n = list[c * NIMG + j];
        float v = S[(size_t)b * NIMG + n];
        if (v > tv[RR - 1]) {
            int p = RR - 1;
            while (p > 0 && tv[p - 1] < v) { tv[p] = tv[p - 1]; ti[p] = ti[p - 1]; p--; }
            tv[p] = v; ti[p] = n;
        }
    }
#pragma unroll
    for (int k = 0; k < RR; k++) { sval[tid * RR + k] = tv[k]; sidx[tid * RR + k] = ti[k]; }
    __syncthreads();

    for (int k = 0; k < RR; k++) {
        float bv = -1e30f; int bp = 0;
        for (int j = tid; j < 256 * RR; j += 256)
            if (sval[j] > bv) { bv = sval[j]; bp = j; }
        redv[tid] = bv; redp[tid] = bp;
        __syncthreads();
        for (int s = 128; s > 0; s >>= 1) {
            if (tid < s && redv[tid + s] > redv[tid]) { redv[tid] = redv[tid + s]; redp[tid] = redp[tid + s]; }
            __syncthreads();
        }
        if (tid == 0) { kv[k] = redv[0]; ki[k] = sidx[redp[0]]; sval[redp[0]] = -1e30f; }
        __syncthreads();
    }

    if (tid == 0) {
        float mx = kv[0], s = 0.f, e[RR];
#pragma unroll
        for (int k = 0; k < RR; k++) { e[k] = expf(kv[k] - mx); s += e[k]; }
        float inv = 1.f / s;
        size_t o = ((size_t)(b * CC) + c) * RR;
#pragma unroll
        for (int k = 0; k < RR; k++) { t_w[o + k] = e[k] * inv; t_idx[o + k] = ki[k]; }
    }
}

// ---------------------------------------------------------------- enhanced_images
__global__ __launch_bounds__(256) void img_kernel(const float* __restrict__ Q,
                                                  const float* __restrict__ I,
                                                  const int* __restrict__ t_idx,
                                                  const float* __restrict__ t_w,
                                                  float* __restrict__ out) {
    int c = blockIdx.x, b = blockIdx.y, tid = threadIdx.x;
    __shared__ float w[RR];
    __shared__ int   id[RR];
    if (tid < RR) {
        size_t o = ((size_t)(b * CC) + c) * RR;
        w[tid] = t_w[o + tid]; id[tid] = t_idx[o + tid];
    }
    __syncthreads();
    for (int d = tid; d < DD; d += 256) {
        float acc = 0.f;
#pragma unroll
        for (int r = 0; r < RR; r++) acc += w[r] * I[(size_t)id[r] * DD + d];
        out[((size_t)(b * CC) + c) * DD + d] = 0.5f * (Q[b * DD + d] + acc);
    }
}

// ---------------------------------------------------------------- gather-transpose
// KT4[c][d4][j] = float4(KN[klist[c][j]][4*d4 .. 4*d4+3]); j >= m clamps to
// class-row 0 (contents valid, masked at top-k). Written once, read 32x.
__global__ __launch_bounds__(256) void transpose_kn(const float* __restrict__ KN,
                                                    const int* __restrict__ kcnt,
                                                    const int* __restrict__ klist,
                                                    float4* __restrict__ KT4) {
    int c = blockIdx.x;
    int w = threadIdx.x >> 6, lane = threadIdx.x & 63;
    int j = blockIdx.y * 4 + w;              // 4 rows per block, 96 blocks.y
    int m = kcnt[c]; if (m > MMAX) m = MMAX;
    int row = klist[c * NKN + (j < m ? j : 0)];
    const float4* src = (const float4*)(KN + (size_t)row * DD);
    float4* dst = KT4 + (size_t)c * (DD / 4) * MMAX;
    float4 v0 = src[lane], v1 = src[lane + 64];
    dst[(size_t)lane * MMAX + j]        = v0;   // reads coalesced per row;
    dst[(size_t)(lane + 64) * MMAX + j] = v1;   // writes 16B-scattered (once)
}

// ---------------------------------------------------------------- knowledge v10
// 8 waves per block (512 thr), wave owns 2 r's -> 4 blocks/CU x 8 waves =
// 32 waves/CU (full 8/SIMD; v9 had 4/SIMD, VALUBusy 72%). Group-skip: only
// ceil(m/64) row-groups are scored (v9 always did 6 -> 33% padding waste).
// Explicit fmaf chains guarantee contraction. Same top-k/select semantics.
__global__ __launch_bounds__(512, 8) void knowledge_kernel(const float* __restrict__ Q,
                                                           const float* __restrict__ I,
                                                           const float* __restrict__ KN,
                                                           const float4* __restrict__ KT4,
                                                           const int* __restrict__ kcnt,
                                                           const int* __restrict__ klist,
                                                           const int* __restrict__ t_idx,
                                                           const float* __restrict__ t_w,
                                                           float* __restrict__ outk) {
    int c = blockIdx.x, b = blockIdx.y;
    int tid = threadIdx.x, wave = tid >> 6, lane = tid & 63;
    int r0 = wave * 2, r1 = r0 + 1;

    __shared__ float4 simg[RR][DD / 4];   // 32 KB, shared by all 8 waves
    __shared__ float  s_iw[RR];
    __shared__ int    s_ii[RR];
    __shared__ float  wgt[RR][KK];
    __shared__ int    kidx[RR][KK];

    if (tid < RR) {
        size_t o = ((size_t)(b * CC) + c) * RR;
        s_iw[tid] = t_w[o + tid]; s_ii[tid] = t_idx[o + tid];
    }
    __syncthreads();

    // cooperative stage: 2048 float4, 4 per thread
    for (int i = tid; i < RR * DD / 4; i += 512) {
        int r = i >> 7, d4 = i & 127;
        simg[r][d4] = ((const float4*)(I + (size_t)s_ii[r] * DD))[d4];
    }

    int m = kcnt[c]; if (m > MMAX) m = MMAX;
    int ng = (m + 63) >> 6;               // row-groups actually populated (1..6)
    const float4* KTc = KT4 + (size_t)c * (DD / 4) * MMAX;

    f2v A0 = 0.f, A1 = 0.f, A2 = 0.f, A3 = 0.f, A4 = 0.f, A5 = 0.f;

    __syncthreads();

    // ---- scoring: group-skip paths, fmaf chains, all subscripts literal
#define LG(g) float4 kk##g = p[g * 64];
#define FG(g, rr, U) A##g[rr] = fmaf(kk##g.x, U.x, fmaf(kk##g.y, U.y, \
                      fmaf(kk##g.z, U.z, fmaf(kk##g.w, U.w, A##g[rr]))));
#define SCORE(LOADS, FMAS) { \
        const float4* p = KTc + lane; \
        for (int d4 = 0; d4 < DD / 4; d4++, p += MMAX) { \
            LOADS \
            float4 u0 = simg[r0][d4]; float4 u1 = simg[r1][d4]; \
            FMAS } }

    if (ng <= 4) {
        SCORE(LG(0) LG(1) LG(2) LG(3),
              FG(0,0,u0) FG(1,0,u0) FG(2,0,u0) FG(3,0,u0)
              FG(0,1,u1) FG(1,1,u1) FG(2,1,u1) FG(3,1,u1))
    } else if (ng == 5) {
        SCORE(LG(0) LG(1) LG(2) LG(3) LG(4),
              FG(0,0,u0) FG(1,0,u0) FG(2,0,u0) FG(3,0,u0) FG(4,0,u0)
              FG(0,1,u1) FG(1,1,u1) FG(2,1,u1) FG(3,1,u1) FG(4,1,u1))
    } else {
        SCORE(LG(0) LG(1) LG(2) LG(3) LG(4) LG(5),
              FG(0,0,u0) FG(1,0,u0) FG(2,0,u0) FG(3,0,u0) FG(4,0,u0) FG(5,0,u0)
              FG(0,1,u1) FG(1,1,u1) FG(2,1,u1) FG(3,1,u1) FG(4,1,u1) FG(5,1,u1))
    }
#undef SCORE
#undef FG
#undef LG

    // ---- per-r top-8 (wave-local shuffle argmax, lexicographic) + softmax
#define CAND(t) { if (!(used & (1u << t)) && \
                      (lv##t > mv || (lv##t == mv && (t * 64 + lane) < mj))) \
                  { mv = lv##t; mj = t * 64 + lane; mt = t; } }

#define ROUND(k) { \
        float mv = -1e30f; int mj = 0x7fffffff; int mt = -1; \
        CAND(0) CAND(1) CAND(2) CAND(3) CAND(4) CAND(5) \
        int cj = mj; \
        for (int off = 32; off > 0; off >>= 1) { \
            float ov = __shfl_xor(mv, off); \
            int   oj = __shfl_xor(mj, off); \
            if (ov > mv || (ov == mv && oj < mj)) { mv = ov; mj = oj; } \
        } \
        if (cj == mj && mt >= 0) used |= (1u << mt); \
        if (lane == k) myj = mj; \
        kv##k = mv; }

#define TOPK_RR(rr) { \
        int r = r0 + rr; \
        float lv0 = (0 * 64 + lane < m) ? A0[rr] : -1e30f; \
        float lv1 = (1 * 64 + lane < m) ? A1[rr] : -1e30f; \
        float lv2 = (2 * 64 + lane < m) ? A2[rr] : -1e30f; \
        float lv3 = (3 * 64 + lane < m) ? A3[rr] : -1e30f; \
        float lv4 = (4 * 64 + lane < m) ? A4[rr] : -1e30f; \
        float lv5 = (5 * 64 + lane < m) ? A5[rr] : -1e30f; \
        unsigned used = 0; int myj = 0; \
        float kv0, kv1, kv2, kv3, kv4, kv5, kv6, kv7; \
        ROUND(0) ROUND(1) ROUND(2) ROUND(3) \
        ROUND(4) ROUND(5) ROUND(6) ROUND(7) \
        if (lane < KK) kidx[r][lane] = klist[c * NKN + myj]; \
        if (lane == 0) { \
            float e0 = 1.f; \
            float e1 = expf(kv1 - kv0), e2 = expf(kv2 - kv0), e3 = expf(kv3 - kv0); \
            float e4 = expf(kv4 - kv0), e5 = expf(kv5 - kv0), e6 = expf(kv6 - kv0); \
            float e7 = expf(kv7 - kv0); \
            float s = e0 + e1 + e2 + e3 + e4 + e5 + e6 + e7; \
            float wr = s_iw[r] / s; \
            wgt[r][0] = e0 * wr; wgt[r][1] = e1 * wr; wgt[r][2] = e2 * wr; \
            wgt[r][3] = e3 * wr; wgt[r][4] = e4 * wr; wgt[r][5] = e5 * wr; \
            wgt[r][6] = e6 * wr; wgt[r][7] = e7 * wr; \
        } }

    TOPK_RR(0) TOPK_RR(1)
#undef TOPK_RR
#undef ROUND
#undef CAND

    __syncthreads();

    // ---- gather-accumulate: 512 threads, one dim each
    float acc0 = 0.f;
#pragma unroll 8
    for (int p = 0; p < RR * KK; p++) {
        int r = p >> 3, k = p & 7;
        float w = wgt[r][k];
        acc0 += w * KN[(size_t)kidx[r][k] * DD + tid];
    }
    size_t o = ((size_t)(b * CC) + c) * DD;
    outk[o + tid] = 0.5f * (Q[b * DD + tid] + acc0);
}

// ---------------------------------------------------------------- launch
extern "C" void kernel_launch(void* const* d_in, const int* in_sizes, int n_in,
                              void* d_out, int out_size, void* d_ws, size_t ws_size,
                              hipStream_t stream) {
    const float* Q  = (const float*)d_in[0];
    const float* I  = (const float*)d_in[1];
    const float* KN = (const float*)d_in[2];
    const int* ilab = (const int*)d_in[3];
    const int* klab = (const int*)d_in[4];

    char* ws = (char*)d_ws;
    float* S        = (float*)ws;  ws += (size_t)BB * NIMG * 4;
    int*   img_list = (int*)ws;    ws += (size_t)CC * NIMG * 4;
    int*   kn_list  = (int*)ws;    ws += (size_t)CC * NKN * 4;
    int*   t_idx    = (int*)ws;    ws += (size_t)BB * CC * RR * 4;
    float* t_w      = (float*)ws;  ws += (size_t)BB * CC * RR * 4;
    int*   img_cnt  = (int*)ws;    ws += CC * 4;
    int*   kn_cnt   = (int*)ws;    ws += CC * 4;
    ws = (char*)(((size_t)ws + 255) & ~(size_t)255);   // align 256B
    float4* KT4     = (float4*)ws; ws += (size_t)CC * (DD / 4) * MMAX * 16;  // 25.2 MB

    float* out_img = (float*)d_out;
    float* out_kn  = out_img + (size_t)BB * CC * DD;

    hipMemsetAsync(img_cnt, 0, 2 * CC * 4, stream);  // img_cnt + kn_cnt contiguous

    build_lists<<<(NIMG + 255) / 256, 256, 0, stream>>>(ilab, NIMG, img_cnt, img_list, NIMG);
    build_lists<<<(NKN  + 255) / 256, 256, 0, stream>>>(klab, NKN,  kn_cnt,  kn_list,  NKN);
    transpose_kn<<<dim3(CC, MMAX / 4), 256, 0, stream>>>(KN, kn_cnt, kn_list, KT4);
    sims_kernel<<<(NIMG + 255) / 256, 256, 0, stream>>>(Q, I, S);
    topk_img<<<dim3(CC, BB), 256, 0, stream>>>(S, img_cnt, img_list, t_idx, t_w);
    img_kernel<<<dim3(CC, BB), 256, 0, stream>>>(Q, I, t_idx, t_w, (float*)d_out);
    knowledge_kernel<<<dim3(CC, BB), 512, 0, stream>>>(Q, I, KN, KT4, kn_cnt, kn_list, t_idx, t_w, out_kn);
}